// Round 3
// baseline (857.304 us; speedup 1.0000x reference)
//
#include <hip/hip_runtime.h>
#include <math.h>

#define T_LEN 1024
#define BATCH 512
#define DIN   12
#define HID   100
#define G4    400
#define MBG   4                   // batches per GROUP, at C-rows {0,4,8,12}
#define NG    2                   // independent groups per block (ILP over stalls)
#define MB    (MBG * NG)          // 8 batches per block
#define NBLK  (BATCH / MB)        // 64
#define AROW  160                 // halves per A row -> 320 B stride
#define NW    8
#define NTHR  (NW * 64)           // 512
#define CHUNK 64
#define UNROLL 8

typedef _Float16 half8   __attribute__((ext_vector_type(8)));
typedef _Float16 half4_t __attribute__((ext_vector_type(4)));
typedef float    f32x4   __attribute__((ext_vector_type(4)));

static __device__ __forceinline__ float fast_exp2(float v) {
#if __has_builtin(__builtin_amdgcn_exp2f)
    return __builtin_amdgcn_exp2f(v);
#else
    return exp2f(v);
#endif
}
static __device__ __forceinline__ float fast_rcp(float v) {
#if __has_builtin(__builtin_amdgcn_rcpf)
    return __builtin_amdgcn_rcpf(v);
#else
    return 1.0f / v;
#endif
}

// LDS-only barrier: __syncthreads() drains vmcnt(0) (global stores!) before
// s_barrier; the only cross-thread data here is LDS, so lgkmcnt(0) suffices.
// Keeps the out-store bursts fully fire-and-forget.
static __device__ __forceinline__ void wg_barrier_lds() {
    __builtin_amdgcn_sched_barrier(0);
    asm volatile("s_waitcnt lgkmcnt(0)" ::: "memory");
    __builtin_amdgcn_s_barrier();
    __builtin_amdgcn_sched_barrier(0);
}

// Two INDEPENDENT batch groups per block, advanced alternately between one
// pair of barriers: group B's MFMA issue overlaps group A's activation
// latency (and vice versa), and the barrier cost is paid once per step-PAIR.
// Weights (bfrag, biasC) are shared across groups; only a[], acc, cs and the
// LDS h-exchange buffers duplicate.
__launch_bounds__(NTHR, 2)
__global__ void lstm_mfma_kernel(const float* __restrict__ x,
                                 const float* __restrict__ Wx,
                                 const float* __restrict__ Wh,
                                 const float* __restrict__ b,
                                 const float* __restrict__ Wd,
                                 const float* __restrict__ bd,
                                 float* __restrict__ out) {
    __shared__ __align__(16) char smem[65536];
    const int tid  = threadIdx.x;
    const int wid  = tid >> 6;
    const int lane = tid & 63;
    const int l    = lane & 15;
    const int quad = lane >> 4;
    const int b0   = blockIdx.x * MB;
    const int j    = wid * 16 + l;

    const float L2E = 1.4426950408889634f;

    // ---------- prologue: B fragments staged through LDS ----------
    _Float16* stage = (_Float16*)smem;      // [8][8][512] halves = 64 KB
    half8 bfrag[4][4];                       // wave 7 uses only bfrag[0] (= Wd cols)
#pragma unroll
    for (int pass = 0; pass < 2; ++pass) {
#pragma unroll
        for (int gg = 0; gg < 2; ++gg) {
            const int G = pass * 2 + gg;
            const float gsc = (G == 2) ? (-2.f * L2E) : (-L2E);  // gate pre-scale
#pragma unroll
            for (int kt = 0; kt < 4; ++kt) {
                half8 v;
#pragma unroll
                for (int jj = 0; jj < 8; ++jj) {
                    const int k = kt * 32 + quad * 8 + jj;
                    float w = 0.f;
                    if (wid < 7) {
                        if (j < HID) {
                            if (k < HID)            w = Wh[k * G4 + G * HID + j] * gsc;
                            else if (k < HID + DIN) w = Wx[(k - HID) * G4 + G * HID + j] * gsc;
                        }
                    } else if (G == 0) {
                        if (l < DIN && k < HID)     w = Wd[k * DIN + l];   // unscaled
                    }
                    v[jj] = (_Float16)w;
                }
                *(half8*)&stage[((wid * 8) + (gg * 4 + kt)) * 512 + lane * 8] = v;
            }
        }
        __syncthreads();
#pragma unroll
        for (int gg = 0; gg < 2; ++gg)
#pragma unroll
            for (int kt = 0; kt < 4; ++kt)
                bfrag[pass * 2 + gg][kt] =
                    *(half8*)&stage[((wid * 8) + (gg * 4 + kt)) * 512 + lane * 8];
        __syncthreads();
    }

    // persistent bias-C registers (C operand of the first MFMA in each chain)
    f32x4 biasC[4];
#pragma unroll
    for (int G = 0; G < 4; ++G) biasC[G] = (f32x4){0.f, 0.f, 0.f, 0.f};
    if (wid < 7) {
        if (j < HID) {
#pragma unroll
            for (int G = 0; G < 4; ++G) {
                const float gsc = (G == 2) ? (-2.f * L2E) : (-L2E);
                const float bv = b[G * HID + j] * gsc;
                biasC[G] = (f32x4){bv, bv, bv, bv};
            }
        }
    } else if (l < DIN) {
        const float bv = bd[l];
        biasC[0] = (f32x4){bv, bv, bv, bv};
    }

    // ---------- LDS after prologue: per-group 4-row A dbuf + x chunk ----------
    _Float16 (*Ah)[2][MBG][AROW] = (_Float16 (*)[2][MBG][AROW])smem; // [NG][2][4][160] = 5120 B
    _Float16* xchunk = (_Float16*)(smem + NG * 2 * MBG * AROW * 2);  // 64*8*12*2 = 12288 B

    auto refill = [&](int c) {    // x[c*64 .. +63] for 8 batches -> fp16 LDS
#pragma unroll
        for (int ii = 0; ii < 3; ++ii) {
            const int f = tid + NTHR * ii;                   // < 1536, always valid
            const int m  = f / (CHUNK * DIN / 4);            // /192 -> 0..7
            const int o  = f - m * (CHUNK * DIN / 4);
            const int tt = o / 3;
            const int dd = o - tt * 3;
            const float4 v = *(const float4*)(x +
                ((size_t)(b0 + m) * T_LEN + c * CHUNK + tt) * DIN + dd * 4);
            half4_t h4;
            h4[0] = (_Float16)v.x; h4[1] = (_Float16)v.y;
            h4[2] = (_Float16)v.z; h4[3] = (_Float16)v.w;
            *(half4_t*)&xchunk[tt * (MB * DIN) + m * DIN + dd * 4] = h4;
        }
    };

    for (int i = tid; i < (NG * 2 * MBG * AROW) / 2; i += NTHR) ((int*)smem)[i] = 0;
    refill(0);
    __syncthreads();
    if (tid < MB * 3) {           // stage x[0] for both groups
        const int m = tid / 3, part = tid - (tid / 3) * 3;
        *(half4_t*)&Ah[m >> 2][0][m & 3][HID + part * 4] =
            *(const half4_t*)&xchunk[m * DIN + part * 4];
    }
    __syncthreads();

    const bool gate_lane = (wid < 7) && (j < HID);
    const int  arow = l >> 2;

    float csA = 0.f, csB = 0.f;   // scaled cell states  c' = -2*log2e * c
    float obufA[UNROLL], obufB[UNROLL];

    // combined-reciprocal LSTM cell on pre-scaled gate sums; updates cs,
    // returns h. zi,zf,zo = -log2e*a ; zg = -2log2e*a (prescaled weights).
    auto cell = [&](const f32x4* acc, float& cs_) -> float {
        const float ei = fast_exp2(acc[0][0]);
        const float ef = fast_exp2(acc[1][0]);
        const float eg = fast_exp2(acc[2][0]);
        const float eo = fast_exp2(acc[3][0]);
        const float gf  = fast_rcp(1.f + ef);
        const float dd  = (1.f + ei) * (1.f + eg);
        const float u   = __builtin_fmaf(eg, 2.f * L2E, -2.f * L2E); // -2log2e*(1-eg)
        const float gig = u * fast_rcp(dd);          // -2log2e * sig(i)*tanh(g)
        cs_ = __builtin_fmaf(gf, cs_, gig);          // c' = gf*c' + gig'
        const float ec = fast_exp2(cs_);             // e^{-2 c}
        return (1.f - ec) * fast_rcp((1.f + eo) * (1.f + ec));
    };

#pragma unroll 1
    for (int tb = 0; tb < T_LEN / UNROLL; ++tb) {
#pragma unroll
        for (int it = 0; it < UNROLL; ++it) {
            const int t  = tb * UNROLL + it;     // always < T_LEN here
            const int p  = it & 1;               // compile-time parity
            const int pn = p ^ 1;

            if (it == UNROLL - 1) {
                // refill next 64-step chunk during step t=64k+63
                if (((tb + 1) & 7) == 0 && (tb + 1) < T_LEN / UNROLL) {
                    refill((tb + 1) >> 3);
                    wg_barrier_lds();
                }
            }

            half8 aA[4], aB[4];
#pragma unroll
            for (int kt = 0; kt < 4; ++kt)
                aA[kt] = *(const half8*)&Ah[0][p][arow][kt * 32 + quad * 8];
#pragma unroll
            for (int kt = 0; kt < 4; ++kt)
                aB[kt] = *(const half8*)&Ah[1][p][arow][kt * 32 + quad * 8];

            if (wid < 7) {
                f32x4 accA[4], accB[4];
                // two independent chained-MFMA sets; compiler interleaves
                // B's issue with A's activation latency (and vice versa)
#pragma unroll
                for (int kt = 0; kt < 4; ++kt)
#pragma unroll
                    for (int G = 0; G < 4; ++G)
                        accA[G] = __builtin_amdgcn_mfma_f32_16x16x32_f16(
                                      aA[kt], bfrag[G][kt],
                                      (kt == 0) ? biasC[G] : accA[G], 0, 0, 0);
#pragma unroll
                for (int kt = 0; kt < 4; ++kt)
#pragma unroll
                    for (int G = 0; G < 4; ++G)
                        accB[G] = __builtin_amdgcn_mfma_f32_16x16x32_f16(
                                      aB[kt], bfrag[G][kt],
                                      (kt == 0) ? biasC[G] : accB[G], 0, 0, 0);

                if (gate_lane) {
                    const float hA = cell(accA, csA);
                    const float hB = cell(accB, csB);
                    Ah[0][pn][quad][j] = (_Float16)hA;
                    Ah[1][pn][quad][j] = (_Float16)hB;
                }
            } else {
                f32x4 accPA, accPB;
#pragma unroll
                for (int kt = 0; kt < 4; ++kt)
                    accPA = __builtin_amdgcn_mfma_f32_16x16x32_f16(
                                aA[kt], bfrag[0][kt],
                                (kt == 0) ? biasC[0] : accPA, 0, 0, 0);
#pragma unroll
                for (int kt = 0; kt < 4; ++kt)
                    accPB = __builtin_amdgcn_mfma_f32_16x16x32_f16(
                                aB[kt], bfrag[0][kt],
                                (kt == 0) ? biasC[0] : accPB, 0, 0, 0);
                obufA[it] = accPA[0];             // out row t-1, col=l
                obufB[it] = accPB[0];
                if ((t + 1) < T_LEN && lane < MB * 3) {   // stage x[t+1], both groups
                    const int m = lane / 3, part = lane - (lane / 3) * 3;
                    *(half4_t*)&Ah[m >> 2][pn][m & 3][HID + part * 4] =
                        *(const half4_t*)&xchunk[((t + 1) & (CHUNK - 1)) * (MB * DIN)
                                                 + m * DIN + part * 4];
                }
            }
            wg_barrier_lds();
        }
        if (wid == 7 && l < DIN) {
            // burst stores, never drained (lgkm-only barriers) -> fire-and-forget
#pragma unroll
            for (int s = 0; s < UNROLL; ++s) {
                const int row = tb * UNROLL + s - 1;
                if (row >= 0) {
                    out[((size_t)(b0 + quad) * T_LEN + row) * DIN + l] = obufA[s];
                    out[((size_t)(b0 + MBG + quad) * T_LEN + row) * DIN + l] = obufB[s];
                }
            }
        }
    }

    // ---------- epilogue: projection of h_{T-1} -> out row T-1, both groups ----------
    if (wid == 7) {
        half8 aA[4], aB[4];
#pragma unroll
        for (int kt = 0; kt < 4; ++kt) {
            aA[kt] = *(const half8*)&Ah[0][0][arow][kt * 32 + quad * 8];
            aB[kt] = *(const half8*)&Ah[1][0][arow][kt * 32 + quad * 8];
        }
        f32x4 accPA, accPB;
#pragma unroll
        for (int kt = 0; kt < 4; ++kt)
            accPA = __builtin_amdgcn_mfma_f32_16x16x32_f16(
                        aA[kt], bfrag[0][kt],
                        (kt == 0) ? biasC[0] : accPA, 0, 0, 0);
#pragma unroll
        for (int kt = 0; kt < 4; ++kt)
            accPB = __builtin_amdgcn_mfma_f32_16x16x32_f16(
                        aB[kt], bfrag[0][kt],
                        (kt == 0) ? biasC[0] : accPB, 0, 0, 0);
        if (l < DIN) {
            out[((size_t)(b0 + quad) * T_LEN + (T_LEN - 1)) * DIN + l] = accPA[0];
            out[((size_t)(b0 + MBG + quad) * T_LEN + (T_LEN - 1)) * DIN + l] = accPB[0];
        }
    }
}

extern "C" void kernel_launch(void* const* d_in, const int* in_sizes, int n_in,
                              void* d_out, int out_size, void* d_ws, size_t ws_size,
                              hipStream_t stream) {
    const float* x  = (const float*)d_in[0];
    const float* Wx = (const float*)d_in[1];
    const float* Wh = (const float*)d_in[2];
    const float* b  = (const float*)d_in[3];
    const float* Wd = (const float*)d_in[4];
    const float* bd = (const float*)d_in[5];
    float* out = (float*)d_out;

    lstm_mfma_kernel<<<NBLK, NTHR, 0, stream>>>(x, Wx, Wh, b, Wd, bd, out);
}

// Round 4
// 642.693 us; speedup vs baseline: 1.3339x; 1.3339x over previous
//
#include <hip/hip_runtime.h>
#include <math.h>

#define T_LEN 1024
#define BATCH 512
#define DIN   12
#define HID   100
#define G4    400
#define MB    4                   // batches per block, at C-rows {0,4,8,12}
#define NBLK  (BATCH / MB)        // 128
#define AROW  160                 // halves per A row -> 320 B stride
#define NW    4                   // 4 waves, 2 col-tiles each
#define NTHR  (NW * 64)           // 256
#define CHUNK 64
#define UNROLL 8

typedef _Float16 half8   __attribute__((ext_vector_type(8)));
typedef _Float16 half4_t __attribute__((ext_vector_type(4)));
typedef float    f32x4   __attribute__((ext_vector_type(4)));

static __device__ __forceinline__ float fast_exp2(float v) {
#if __has_builtin(__builtin_amdgcn_exp2f)
    return __builtin_amdgcn_exp2f(v);
#else
    return exp2f(v);
#endif
}
static __device__ __forceinline__ float fast_rcp(float v) {
#if __has_builtin(__builtin_amdgcn_rcpf)
    return __builtin_amdgcn_rcpf(v);
#else
    return 1.0f / v;
#endif
}

// LDS-only barrier (no vmcnt drain): out-store bursts stay fire-and-forget.
static __device__ __forceinline__ void wg_barrier_lds() {
    __builtin_amdgcn_sched_barrier(0);
    asm volatile("s_waitcnt lgkmcnt(0)" ::: "memory");
    __builtin_amdgcn_s_barrier();
    __builtin_amdgcn_sched_barrier(0);
}

// 4-wave restructure: wave w owns col-tiles {w, w+4} (j = tile*16 + l).
//   waves 0-2: two gate tiles (32 MFMAs/step, 2 cells/lane)
//   wave 3  : gate tile 3 + Wd projection (20 MFMAs) + x staging + stores
// Rationale: 8-wave version measured 1164 cy/step vs ~500 cy chain model;
// round-3 showed the gap is NOT fillable by in-wave ILP -> fixed overhead
// (8-wave barrier skew + 2 lockstep waves/SIMD contention). This halves the
// barrier width and (via ~240 VGPR) runs 1 wave/SIMD with 2x issue density.
__launch_bounds__(NTHR, 1)
__global__ void lstm_mfma_kernel(const float* __restrict__ x,
                                 const float* __restrict__ Wx,
                                 const float* __restrict__ Wh,
                                 const float* __restrict__ b,
                                 const float* __restrict__ Wd,
                                 const float* __restrict__ bd,
                                 float* __restrict__ out) {
    __shared__ __align__(16) char smem[32768];
    const int tid  = threadIdx.x;
    const int wid  = tid >> 6;
    const int lane = tid & 63;
    const int l    = lane & 15;
    const int quad = lane >> 4;
    const int b0   = blockIdx.x * MB;

    const float L2E = 1.4426950408889634f;

    // ---------- prologue: B fragments staged through LDS (defeats remat) ----------
    _Float16* stage = (_Float16*)smem;      // [4][8][512] halves = 32 KB
    half8 bfrag[2][4][4];                    // [tile][gate][kt]; wave3 tile1 = Wd
#pragma unroll
    for (int pass = 0; pass < 4; ++pass) {
        const int ti = pass >> 1;
#pragma unroll
        for (int gg = 0; gg < 2; ++gg) {
            const int G = (pass & 1) * 2 + gg;
            const float gsc = (G == 2) ? (-2.f * L2E) : (-L2E);  // gate pre-scale
#pragma unroll
            for (int kt = 0; kt < 4; ++kt) {
                half8 v;
#pragma unroll
                for (int jj = 0; jj < 8; ++jj) {
                    const int k = kt * 32 + quad * 8 + jj;
                    float w = 0.f;
                    if (!(wid == 3 && ti == 1)) {
                        const int tt = (ti == 0) ? wid : wid + 4;
                        const int jc = tt * 16 + l;
                        if (jc < HID) {
                            if (k < HID)            w = Wh[k * G4 + G * HID + jc] * gsc;
                            else if (k < HID + DIN) w = Wx[(k - HID) * G4 + G * HID + jc] * gsc;
                        }
                    } else if (G == 0) {
                        if (l < DIN && k < HID)     w = Wd[k * DIN + l];   // unscaled
                    }
                    v[jj] = (_Float16)w;
                }
                *(half8*)&stage[((wid * 8) + (gg * 4 + kt)) * 512 + lane * 8] = v;
            }
        }
        __syncthreads();
#pragma unroll
        for (int gg = 0; gg < 2; ++gg)
#pragma unroll
            for (int kt = 0; kt < 4; ++kt)
                bfrag[ti][(pass & 1) * 2 + gg][kt] =
                    *(half8*)&stage[((wid * 8) + (gg * 4 + kt)) * 512 + lane * 8];
        __syncthreads();
    }

    // persistent bias-C registers (C operand of the first MFMA in each chain)
    f32x4 biasC[2][4];
#pragma unroll
    for (int ti = 0; ti < 2; ++ti)
#pragma unroll
        for (int G = 0; G < 4; ++G) biasC[ti][G] = (f32x4){0.f, 0.f, 0.f, 0.f};
    {
        const int jc0 = wid * 16 + l;                 // tile ti=0: always < 100
#pragma unroll
        for (int G = 0; G < 4; ++G) {
            const float gsc = (G == 2) ? (-2.f * L2E) : (-L2E);
            const float bv = b[G * HID + jc0] * gsc;
            biasC[0][G] = (f32x4){bv, bv, bv, bv};
        }
        if (wid < 3) {
            const int jc1 = (wid + 4) * 16 + l;
            if (jc1 < HID) {
#pragma unroll
                for (int G = 0; G < 4; ++G) {
                    const float gsc = (G == 2) ? (-2.f * L2E) : (-L2E);
                    const float bv = b[G * HID + jc1] * gsc;
                    biasC[1][G] = (f32x4){bv, bv, bv, bv};
                }
            }
        } else if (l < DIN) {
            const float bv = bd[l];
            biasC[1][0] = (f32x4){bv, bv, bv, bv};
        }
    }

    // ---------- LDS after prologue: 4-row A dbuf (320B stride) + x chunk ----------
    _Float16 (*Ah)[MB][AROW] = (_Float16 (*)[MB][AROW])smem;     // 2*4*160*2 = 2560 B
    _Float16* xchunk = (_Float16*)(smem + 2560);                 // 64*48*2 = 6144 B

    auto refill = [&](int c) {    // x[c*64 .. +63] for 4 batches -> fp16 LDS
#pragma unroll
        for (int ii = 0; ii < 3; ++ii) {
            const int f = tid + NTHR * ii;                   // < 768, always valid
            const int m  = f / (CHUNK * DIN / 4);            // /192
            const int o  = f - m * (CHUNK * DIN / 4);
            const int tt = o / 3;
            const int dd = o - tt * 3;
            const float4 v = *(const float4*)(x +
                ((size_t)(b0 + m) * T_LEN + c * CHUNK + tt) * DIN + dd * 4);
            half4_t h4;
            h4[0] = (_Float16)v.x; h4[1] = (_Float16)v.y;
            h4[2] = (_Float16)v.z; h4[3] = (_Float16)v.w;
            *(half4_t*)&xchunk[tt * (MB * DIN) + m * DIN + dd * 4] = h4;
        }
    };

    for (int i = tid; i < (2 * MB * AROW) / 2; i += NTHR) ((int*)smem)[i] = 0;
    refill(0);
    __syncthreads();
    if (tid < MB * 3) {           // stage x[0]
        const int m = tid / 3, part = tid - (tid / 3) * 3;
        *(half4_t*)&Ah[0][m][HID + part * 4] =
            *(const half4_t*)&xchunk[m * DIN + part * 4];
    }
    __syncthreads();

    const int arow = l >> 2;

    float csA = 0.f, csB = 0.f;   // scaled cell states  c' = -2*log2e * c
    float obuf[UNROLL];

    // combined-reciprocal LSTM cell on pre-scaled gate sums; updates cs,
    // returns h. zi,zf,zo = -log2e*a ; zg = -2log2e*a (prescaled weights).
    auto cell = [&](const f32x4* acc, float& cs_) -> float {
        const float ei = fast_exp2(acc[0][0]);
        const float ef = fast_exp2(acc[1][0]);
        const float eg = fast_exp2(acc[2][0]);
        const float eo = fast_exp2(acc[3][0]);
        const float gf  = fast_rcp(1.f + ef);
        const float dd  = (1.f + ei) * (1.f + eg);
        const float u   = __builtin_fmaf(eg, 2.f * L2E, -2.f * L2E); // -2log2e*(1-eg)
        const float gig = u * fast_rcp(dd);          // -2log2e * sig(i)*tanh(g)
        cs_ = __builtin_fmaf(gf, cs_, gig);          // c' = gf*c' + gig'
        const float ec = fast_exp2(cs_);             // e^{-2 c}
        return (1.f - ec) * fast_rcp((1.f + eo) * (1.f + ec));
    };

#pragma unroll 1
    for (int tb = 0; tb < T_LEN / UNROLL; ++tb) {
#pragma unroll
        for (int it = 0; it < UNROLL; ++it) {
            const int t  = tb * UNROLL + it;     // always < T_LEN here
            const int p  = it & 1;               // compile-time parity
            const int pn = p ^ 1;

            if (it == UNROLL - 1) {
                // refill next 64-step chunk during step t=64k+63
                if (((tb + 1) & 7) == 0 && (tb + 1) < T_LEN / UNROLL) {
                    refill((tb + 1) >> 3);
                    wg_barrier_lds();
                }
            }

            half8 a[4];
#pragma unroll
            for (int kt = 0; kt < 4; ++kt)
                a[kt] = *(const half8*)&Ah[p][arow][kt * 32 + quad * 8];

            if (wid < 3) {
                // 8 interleaved depth-4 chains: dependent MFMAs ~8 issues
                // apart -> chain latency hidden under issue.
                f32x4 acc[2][4];
#pragma unroll
                for (int kt = 0; kt < 4; ++kt)
#pragma unroll
                    for (int ti = 0; ti < 2; ++ti)
#pragma unroll
                        for (int G = 0; G < 4; ++G)
                            acc[ti][G] = __builtin_amdgcn_mfma_f32_16x16x32_f16(
                                             a[kt], bfrag[ti][G][kt],
                                             (kt == 0) ? biasC[ti][G] : acc[ti][G], 0, 0, 0);

                const float hA = cell(acc[0], csA);
                const float hB = cell(acc[1], csB);
                Ah[pn][quad][wid * 16 + l] = (_Float16)hA;
                if (wid < 2 || l < 4)                    // tile 6 covers j=96..99
                    Ah[pn][quad][(wid + 4) * 16 + l] = (_Float16)hB;
            } else {
                // wave 3: gate tile 3 + projection + x staging (light wave)
                f32x4 acc3[4], accP;
#pragma unroll
                for (int kt = 0; kt < 4; ++kt) {
#pragma unroll
                    for (int G = 0; G < 4; ++G)
                        acc3[G] = __builtin_amdgcn_mfma_f32_16x16x32_f16(
                                      a[kt], bfrag[0][G][kt],
                                      (kt == 0) ? biasC[0][G] : acc3[G], 0, 0, 0);
                    accP = __builtin_amdgcn_mfma_f32_16x16x32_f16(
                               a[kt], bfrag[1][0][kt],
                               (kt == 0) ? biasC[1][0] : accP, 0, 0, 0);
                }
                const float h3 = cell(acc3, csA);
                Ah[pn][quad][48 + l] = (_Float16)h3;
                obuf[it] = accP[0];               // out row t-1, batch=quad, col=l
                if ((t + 1) < T_LEN && lane < MB * 3) {   // stage x[t+1]
                    const int m = lane / 3, part = lane - (lane / 3) * 3;
                    *(half4_t*)&Ah[pn][m][HID + part * 4] =
                        *(const half4_t*)&xchunk[((t + 1) & (CHUNK - 1)) * (MB * DIN)
                                                 + m * DIN + part * 4];
                }
            }
            wg_barrier_lds();
        }
        if (wid == 3 && l < DIN) {
            // burst stores, never drained (lgkm-only barriers) -> fire-and-forget
#pragma unroll
            for (int s = 0; s < UNROLL; ++s) {
                const int row = tb * UNROLL + s - 1;
                if (row >= 0)
                    out[((size_t)(b0 + quad) * T_LEN + row) * DIN + l] = obuf[s];
            }
        }
    }

    // ---------- epilogue: projection of h_{T-1} -> out row T-1 ----------
    if (wid == 3) {
        half8 a[4];
#pragma unroll
        for (int kt = 0; kt < 4; ++kt)
            a[kt] = *(const half8*)&Ah[0][arow][kt * 32 + quad * 8];
        f32x4 accP;
#pragma unroll
        for (int kt = 0; kt < 4; ++kt)
            accP = __builtin_amdgcn_mfma_f32_16x16x32_f16(
                       a[kt], bfrag[1][0][kt],
                       (kt == 0) ? biasC[1][0] : accP, 0, 0, 0);
        if (l < DIN)
            out[((size_t)(b0 + quad) * T_LEN + (T_LEN - 1)) * DIN + l] = accP[0];
    }
}

extern "C" void kernel_launch(void* const* d_in, const int* in_sizes, int n_in,
                              void* d_out, int out_size, void* d_ws, size_t ws_size,
                              hipStream_t stream) {
    const float* x  = (const float*)d_in[0];
    const float* Wx = (const float*)d_in[1];
    const float* Wh = (const float*)d_in[2];
    const float* b  = (const float*)d_in[3];
    const float* Wd = (const float*)d_in[4];
    const float* bd = (const float*)d_in[5];
    float* out = (float*)d_out;

    lstm_mfma_kernel<<<NBLK, NTHR, 0, stream>>>(x, Wx, Wh, b, Wd, bd, out);
}